// Round 8
// baseline (218.490 us; speedup 1.0000x reference)
//
#include <hip/hip_runtime.h>
#include <hip/hip_bf16.h>
#include <stdint.h>

using bf16 = __hip_bfloat16;
typedef __attribute__((ext_vector_type(8))) short bf16x8;
typedef __attribute__((ext_vector_type(4))) float f32x4;
typedef __attribute__((ext_vector_type(16))) float f32x16;

#define BATCHN 512

// ================= merged prologue: halo-zero x3, wprep x3, gating =================
__device__ __forceinline__ void zero_halo_dev(bf16* buf, int H, int W, int C, int idx) {
  int nvec = C >> 3;
  int P = 2 * (W + 2) + 2 * H;
  if (idx >= BATCHN * P * nvec) return;
  int cv = idx % nvec;
  int p = (idx / nvec) % P;
  int b = idx / (nvec * P);
  int row, col;
  if (p < W + 2) { row = 0; col = p; }
  else if (p < 2 * (W + 2)) { row = H + 1; col = p - (W + 2); }
  else { int q = p - 2 * (W + 2); row = 1 + (q >> 1); col = (q & 1) ? (W + 1) : 0; }
  float4 z4 = {0.f, 0.f, 0.f, 0.f};
  *(float4*)(buf + ((size_t)(b * (H + 2) + row) * (W + 2) + col) * C + cv * 8) = z4;
}

// wt layout (shape-agnostic k8-groups): wt[((chunk*(IC/8) + kg)*OCp + oc)*8 + e], ic = kg*8+e
__device__ __forceinline__ void wprep_dev(const float* w, bf16* wt, int IC, int OCr, int OCp, int idx) {
  int KG = IC / 8;
  if (idx >= 16 * OCp * IC) return;
  int e = idx & 7;
  int t = idx >> 3;
  int oc = t % OCp; t /= OCp;
  int kg = t % KG; t /= KG;
  int tap = t & 3, p = t >> 2;
  int ic = kg * 8 + e;
  int dy = tap >> 1, dx = tap & 1;
  int py = p >> 1, px = p & 1;
  const int ktab[2][2] = {{1, 3}, {2, 0}};
  int ky = ktab[py][dy], kx = ktab[px][dx];
  float v = 0.f;
  if (oc < OCr) v = w[((ic * OCr + oc) * 4 + ky) * 4 + kx];
  wt[idx] = __float2bfloat16(v);
}

#define NB_Z1 1152
#define NB_Z2 2176
#define NB_Z3 2112
#define NB_W1 1024
#define NB_W2 512
#define NB_W3 64
#define NB_G  128

__global__ void prep_kernel(bf16* x1, bf16* x2, bf16* x3,
                            const float* w1, bf16* wt1, const float* w2, bf16* wt2,
                            const float* w3, bf16* wt3,
                            const float* x, const float* gw, const float* gb, float* lp) {
  int bid = blockIdx.x;
  int tid = threadIdx.x;
  if (bid < NB_Z1) { zero_halo_dev(x1, 8, 8, 128, bid * 256 + tid); return; }
  bid -= NB_Z1;
  if (bid < NB_Z2) { zero_halo_dev(x2, 16, 16, 128, bid * 256 + tid); return; }
  bid -= NB_Z2;
  if (bid < NB_Z3) { zero_halo_dev(x3, 32, 32, 64, bid * 256 + tid); return; }
  bid -= NB_Z3;
  if (bid < NB_W1) { wprep_dev(w1, wt1, 128, 128, 128, bid * 256 + tid); return; }
  bid -= NB_W1;
  if (bid < NB_W2) { wprep_dev(w2, wt2, 128, 64, 64, bid * 256 + tid); return; }
  bid -= NB_W2;
  if (bid < NB_W3) { wprep_dev(w3, wt3, 64, 3, 16, bid * 256 + tid); return; }
  bid -= NB_W3;
  __shared__ float xs[4][128];
  __shared__ float gs[4][32];
  const int sub = tid >> 6, t = tid & 63;
  const int b = bid * 4 + sub;
  xs[sub][t] = x[b * 128 + t];
  xs[sub][t + 64] = x[b * 128 + 64 + t];
  __syncthreads();
  if (t < 31) {
    float acc = gb[t];
    #pragma unroll 8
    for (int k = 0; k < 128; ++k) acc += xs[sub][k] * gw[k * 31 + t];
    gs[sub][t] = 1.f / (1.f + __expf(-acc));
  }
  __syncthreads();
  if (t < 32) {
    float prob = 1.f;
    #pragma unroll
    for (int d = 1; d <= 5; ++d) {
      int i = t >> (6 - d);
      int node = (1 << (d - 1)) - 1 + i;
      float gv = gs[sub][node];
      prob *= ((t >> (5 - d)) & 1) ? (1.f - gv) : gv;
    }
    lp[b * 32 + t] = prob;
  }
}

// ---------------- mixture ----------------
__global__ void mixture_kernel(const float* __restrict__ z, const float* __restrict__ lp,
                               bf16* __restrict__ x1) {
  __shared__ float lps[64 * 32];
  const int s = blockIdx.x;
  const int h = s >> 3, w = s & 7;
  const int b0 = blockIdx.y * 64;
  const int t = threadIdx.x;
  const int c = t & 127;
  const int half = t >> 7;
  float4 zr[8];
  const float4* zp = (const float4*)(z + (size_t)(c * 64 + s) * 32);
  #pragma unroll
  for (int i = 0; i < 8; ++i) zr[i] = zp[i];
  #pragma unroll
  for (int i = 0; i < 8; ++i) lps[t + 256 * i] = lp[b0 * 32 + t + 256 * i];
  __syncthreads();
  for (int bs = 0; bs < 32; ++bs) {
    int bl = half * 32 + bs;
    const float4* lr = (const float4*)(lps + bl * 32);
    float acc = 0.f;
    #pragma unroll
    for (int i = 0; i < 8; ++i) {
      float4 l4 = lr[i];
      acc += zr[i].x * l4.x + zr[i].y * l4.y + zr[i].z * l4.z + zr[i].w * l4.w;
    }
    int b = b0 + bl;
    x1[((size_t)(b * 10 + h + 1) * 10 + (w + 1)) * 128 + c] = __float2bfloat16(acc);
  }
}

// shift-class tables: 9 classes cover the 16 (parity,tap) pairs with shared A shifts
#define CLASS_TABLES \
  constexpr int TAPA[9] = {0, 1, 1, 2, 2, 3, 3, 3, 3}; \
  constexpr int DYA[9]  = {0, 0, 0,-1, 1,-1,-1, 1, 1}; \
  constexpr int DXA[9]  = {0,-1, 1, 0, 0,-1, 1,-1, 1}; \
  constexpr int MSK[9]  = {0xF,0x5,0xA,0x3,0xC,0x1,0x2,0x4,0x8};

// ---------------- 32x32x16 parity-fused transposed conv (conv1, conv2) ----------------
// A staged once in LDS [kg][pix][8]; per shift-class one A b128 read feeds up to 4 MFMAs
// (one per parity in the class mask). B fragments global->VGPR (L1/L2-resident wt).
template<int IC, int OCp, int IH, int IW, int ROWS>
__global__ __launch_bounds__(256, 3)
void convt32(const bf16* __restrict__ xin, const bf16* __restrict__ wt,
             const float* __restrict__ bias, bf16* __restrict__ xout) {
  constexpr int KG = IC / 8;
  constexpr int NS = IC / 16;          // k16 steps per tap
  constexpr int IH2 = IH + 2, IW2 = IW + 2;
  constexpr int OH2 = 2 * IH + 2, OW2 = 2 * IW + 2;
  constexpr int NPIX = (ROWS + 2) * IW2;
  constexpr int BPI = IH / ROWS;
  constexpr int LIW = (IW == 8 ? 3 : 4);
  constexpr int ICV = IC / 8;
  __shared__ bf16 Alds[KG * NPIX * 8];

  const int tid = threadIdx.x;
  const int wave = tid >> 6, lane = tid & 63;
  const int hl = lane >> 5, l32 = lane & 31;
  const int wm = wave >> 1, wn = wave & 1;
  const int img = blockIdx.x / BPI;
  const int tb = blockIdx.x % BPI;
  const int n0 = blockIdx.y * 64;

  // stage A tile: global [pix][ic] -> LDS [kg][pix][8]
  const bf16* src = xin + ((size_t)img * IH2 + tb * ROWS) * IW2 * IC;
  for (int g = tid; g < NPIX * ICV; g += 256) {
    const int pix = g / ICV;
    const int gr = g % ICV;
    const float4 v = *(const float4*)(src + (size_t)g * 8);
    *(float4*)(&Alds[(gr * NPIX + pix) * 8]) = v;
  }

  // per-lane pointers
  const int m = wm * 32 + l32;
  const int cpix = ((m >> LIW) + 1) * IW2 + (m & (IW - 1)) + 1;
  const bf16* wtp = wt + (size_t)(n0 + wn * 32 + l32) * 8;

  f32x16 acc[4];
  #pragma unroll
  for (int p = 0; p < 4; ++p)
    #pragma unroll
    for (int r = 0; r < 16; ++r) acc[p][r] = 0.f;

  CLASS_TABLES
  __syncthreads();

  #pragma unroll
  for (int e = 0; e < 9; ++e) {
    const int tap = TAPA[e];
    const int sh = (DYA[e] * IW2 + DXA[e]);
    #pragma unroll
    for (int s = 0; s < NS; ++s) {
      const bf16x8 a = *(const bf16x8*)(Alds + (((s * 2 + hl) * NPIX) + cpix + sh) * 8);
      #pragma unroll
      for (int p = 0; p < 4; ++p) {
        if (MSK[e] & (1 << p)) {
          const int chunk = p * 4 + tap;
          const bf16x8 b = *(const bf16x8*)(wtp + ((size_t)(chunk * KG + s * 2 + hl) * OCp) * 8);
          acc[p] = __builtin_amdgcn_mfma_f32_32x32x16_bf16(a, b, acc[p], 0, 0, 0);
        }
      }
    }
  }

  // epilogue: C/D col = lane&31, row = (r&3) + 8*(r>>2) + 4*(lane>>5)
  const int oc = n0 + wn * 32 + l32;
  const float bv = bias[oc];
  #pragma unroll
  for (int p = 0; p < 4; ++p) {
    const int py = p >> 1, px = p & 1;
    #pragma unroll
    for (int r = 0; r < 16; ++r) {
      const int ml = wm * 32 + (r & 3) + 8 * (r >> 2) + 4 * hl;
      const int y = tb * ROWS + (ml >> LIW), x = ml & (IW - 1);
      float v = fmaxf(acc[p][r] + bv, 0.f);
      xout[(((size_t)img * OH2 + 2 * y + py + 1) * OW2 + 2 * x + px + 1) * OCp + oc] =
          __float2bfloat16(v);
    }
  }
}

// ---------------- 16x16x32 conv3 (N=16, fp32 NCHW out), class-shared A & B ----------------
__global__ __launch_bounds__(256, 3)
void convt16_final(const bf16* __restrict__ xin, const bf16* __restrict__ wt,
                   const float* __restrict__ bias, float* __restrict__ fout) {
  constexpr int IC = 64, OCp = 16, OCr = 3, IH = 32, IW = 32, ROWS = 8;
  constexpr int KG = IC / 8;
  constexpr int NC = IC / 32;
  constexpr int IH2 = IH + 2, IW2 = IW + 2;
  constexpr int NPIX = (ROWS + 2) * IW2;
  constexpr int BPI = IH / ROWS;
  constexpr int MI = 4;
  constexpr int ICV = IC / 8;
  __shared__ bf16 Alds[KG * NPIX * 8];

  const int tid = threadIdx.x;
  const int wave = tid >> 6, lane = tid & 63;
  const int q = lane >> 4, li = lane & 15;
  const int img = blockIdx.x / BPI;
  const int tb = blockIdx.x % BPI;

  const bf16* src = xin + ((size_t)img * IH2 + tb * ROWS) * IW2 * IC;
  for (int g = tid; g < NPIX * ICV; g += 256) {
    const int pix = g / ICV;
    const int gr = g % ICV;
    const float4 v = *(const float4*)(src + (size_t)g * 8);
    *(float4*)(&Alds[(gr * NPIX + pix) * 8]) = v;
  }

  int cpix[MI];
  #pragma unroll
  for (int mi = 0; mi < MI; ++mi) {
    const int m = wave * 64 + mi * 16 + li;
    cpix[mi] = ((m >> 5) + 1) * IW2 + (m & 31) + 1;
  }
  const bf16* wtp = wt + (size_t)li * 8;

  f32x4 acc[4][MI];
  #pragma unroll
  for (int p = 0; p < 4; ++p)
    #pragma unroll
    for (int mi = 0; mi < MI; ++mi)
      acc[p][mi] = (f32x4){0.f, 0.f, 0.f, 0.f};

  CLASS_TABLES
  __syncthreads();

  #pragma unroll
  for (int e = 0; e < 9; ++e) {
    const int tap = TAPA[e];
    const int sh = (DYA[e] * IW2 + DXA[e]);
    #pragma unroll
    for (int c = 0; c < NC; ++c) {
      // B fragments for this (class, c): shared across all MI m-tiles
      bf16x8 bfr[4];
      #pragma unroll
      for (int p = 0; p < 4; ++p)
        if (MSK[e] & (1 << p))
          bfr[p] = *(const bf16x8*)(wtp + ((size_t)((p * 4 + tap) * KG + c * 4 + q) * OCp) * 8);
      #pragma unroll
      for (int mi = 0; mi < MI; ++mi) {
        const bf16x8 a = *(const bf16x8*)(Alds + (((c * 4 + q) * NPIX) + cpix[mi] + sh) * 8);
        #pragma unroll
        for (int p = 0; p < 4; ++p)
          if (MSK[e] & (1 << p))
            acc[p][mi] = __builtin_amdgcn_mfma_f32_16x16x32_bf16(a, bfr[p], acc[p][mi], 0, 0, 0);
      }
    }
  }

  // epilogue: fp32 NCHW, float2 px-pairs. C/D row = q*4+r, col = li
  const int oc = li;
  if (oc < OCr) {
    const float bv = bias[oc];
    #pragma unroll
    for (int py = 0; py < 2; ++py)
      #pragma unroll
      for (int mi = 0; mi < MI; ++mi)
        #pragma unroll
        for (int r = 0; r < 4; ++r) {
          const int pix = (wave * MI + mi) * 16 + q * 4 + r;
          const int y = tb * ROWS + (pix >> 5), x = pix & 31;
          float2 v2;
          v2.x = acc[py * 2 + 0][mi][r] + bv;
          v2.y = acc[py * 2 + 1][mi][r] + bv;
          *(float2*)(&fout[(((size_t)img * 3 + oc) * 64 + 2 * y + py) * 64 + 2 * x]) = v2;
        }
  }
}

// ---------------- launch ----------------
extern "C" void kernel_launch(void* const* d_in, const int* in_sizes, int n_in,
                              void* d_out, int out_size, void* d_ws, size_t ws_size,
                              hipStream_t stream) {
  const float* x  = (const float*)d_in[0];
  const float* gw = (const float*)d_in[1];
  const float* gb = (const float*)d_in[2];
  const float* z  = (const float*)d_in[3];
  const float* w1 = (const float*)d_in[4];
  const float* b1 = (const float*)d_in[5];
  const float* w2 = (const float*)d_in[6];
  const float* b2 = (const float*)d_in[7];
  const float* w3 = (const float*)d_in[8];
  const float* b3 = (const float*)d_in[9];
  float* out = (float*)d_out;

  char* w = (char*)d_ws;
  float* lp  = (float*)(w);
  bf16* x1  = (bf16*)(w + 65536);
  bf16* x2  = (bf16*)(w + 13172736);
  bf16* x3  = (bf16*)(w + 55640064);
  bf16* wt1 = (bf16*)(w + 131399680);
  bf16* wt2 = (bf16*)(w + 131923968);
  bf16* wt3 = (bf16*)(w + 132186112);

  prep_kernel<<<NB_Z1 + NB_Z2 + NB_Z3 + NB_W1 + NB_W2 + NB_W3 + NB_G, 256, 0, stream>>>(
      x1, x2, x3, w1, wt1, w2, wt2, w3, wt3, x, gw, gb, lp);

  mixture_kernel<<<dim3(64, 8), 256, 0, stream>>>(z, lp, x1);

  // conv1: 128->128, 8x8 -> 16x16. M=64/img (whole image), N split 2x64. 1024 blocks.
  convt32<128, 128, 8, 8, 8><<<dim3(512, 2), 256, 0, stream>>>(x1, wt1, b1, x2);
  // conv2: 128->64, 16x16 -> 32x32. ROWS=4 -> M=64/block, N=64. 2048 blocks.
  convt32<128, 64, 16, 16, 4><<<dim3(2048, 1), 256, 0, stream>>>(x2, wt2, b2, x3);
  // conv3: 64->3(pad16), 32x32 -> 64x64, fp32 NCHW. ROWS=8 -> M=256/block. 2048 blocks.
  convt16_final<<<dim3(2048, 1), 256, 0, stream>>>(x3, wt3, b3, out);
}

// Round 9
// 196.018 us; speedup vs baseline: 1.1146x; 1.1146x over previous
//
#include <hip/hip_runtime.h>
#include <hip/hip_bf16.h>
#include <stdint.h>

using bf16 = __hip_bfloat16;
typedef __attribute__((ext_vector_type(8))) short bf16x8;
typedef __attribute__((ext_vector_type(4))) float f32x4;
typedef __attribute__((ext_vector_type(16))) float f32x16;

#define BATCHN 512

// ================= merged prologue: halo-zero x3, wprep x3, gating =================
__device__ __forceinline__ void zero_halo_dev(bf16* buf, int H, int W, int C, int idx) {
  int nvec = C >> 3;
  int P = 2 * (W + 2) + 2 * H;
  if (idx >= BATCHN * P * nvec) return;
  int cv = idx % nvec;
  int p = (idx / nvec) % P;
  int b = idx / (nvec * P);
  int row, col;
  if (p < W + 2) { row = 0; col = p; }
  else if (p < 2 * (W + 2)) { row = H + 1; col = p - (W + 2); }
  else { int q = p - 2 * (W + 2); row = 1 + (q >> 1); col = (q & 1) ? (W + 1) : 0; }
  float4 z4 = {0.f, 0.f, 0.f, 0.f};
  *(float4*)(buf + ((size_t)(b * (H + 2) + row) * (W + 2) + col) * C + cv * 8) = z4;
}

// wt layout: wt[((chunk*(IC/8) + kg)*OCp + oc)*8 + e], chunk = p*4+tap, ic = kg*8+e
__device__ __forceinline__ void wprep_dev(const float* w, bf16* wt, int IC, int OCr, int OCp, int idx) {
  int KG = IC / 8;
  if (idx >= 16 * OCp * IC) return;
  int e = idx & 7;
  int t = idx >> 3;
  int oc = t % OCp; t /= OCp;
  int kg = t % KG; t /= KG;
  int tap = t & 3, p = t >> 2;
  int ic = kg * 8 + e;
  int dy = tap >> 1, dx = tap & 1;
  int py = p >> 1, px = p & 1;
  const int ktab[2][2] = {{1, 3}, {2, 0}};
  int ky = ktab[py][dy], kx = ktab[px][dx];
  float v = 0.f;
  if (oc < OCr) v = w[((ic * OCr + oc) * 4 + ky) * 4 + kx];
  wt[idx] = __float2bfloat16(v);
}

#define NB_Z1 1152
#define NB_Z2 2176
#define NB_Z3 2112
#define NB_W1 1024
#define NB_W2 512
#define NB_W3 64
#define NB_G  128

__global__ void prep_kernel(bf16* x1, bf16* x2, bf16* x3,
                            const float* w1, bf16* wt1, const float* w2, bf16* wt2,
                            const float* w3, bf16* wt3,
                            const float* x, const float* gw, const float* gb, float* lp) {
  int bid = blockIdx.x;
  int tid = threadIdx.x;
  if (bid < NB_Z1) { zero_halo_dev(x1, 8, 8, 128, bid * 256 + tid); return; }
  bid -= NB_Z1;
  if (bid < NB_Z2) { zero_halo_dev(x2, 16, 16, 128, bid * 256 + tid); return; }
  bid -= NB_Z2;
  if (bid < NB_Z3) { zero_halo_dev(x3, 32, 32, 64, bid * 256 + tid); return; }
  bid -= NB_Z3;
  if (bid < NB_W1) { wprep_dev(w1, wt1, 128, 128, 128, bid * 256 + tid); return; }
  bid -= NB_W1;
  if (bid < NB_W2) { wprep_dev(w2, wt2, 128, 64, 64, bid * 256 + tid); return; }
  bid -= NB_W2;
  if (bid < NB_W3) { wprep_dev(w3, wt3, 64, 3, 16, bid * 256 + tid); return; }
  bid -= NB_W3;
  __shared__ float xs[4][128];
  __shared__ float gs[4][32];
  const int sub = tid >> 6, t = tid & 63;
  const int b = bid * 4 + sub;
  xs[sub][t] = x[b * 128 + t];
  xs[sub][t + 64] = x[b * 128 + 64 + t];
  __syncthreads();
  if (t < 31) {
    float acc = gb[t];
    #pragma unroll 8
    for (int k = 0; k < 128; ++k) acc += xs[sub][k] * gw[k * 31 + t];
    gs[sub][t] = 1.f / (1.f + __expf(-acc));
  }
  __syncthreads();
  if (t < 32) {
    float prob = 1.f;
    #pragma unroll
    for (int d = 1; d <= 5; ++d) {
      int i = t >> (6 - d);
      int node = (1 << (d - 1)) - 1 + i;
      float gv = gs[sub][node];
      prob *= ((t >> (5 - d)) & 1) ? (1.f - gv) : gv;
    }
    lp[b * 32 + t] = prob;
  }
}

// ---------------- mixture ----------------
__global__ void mixture_kernel(const float* __restrict__ z, const float* __restrict__ lp,
                               bf16* __restrict__ x1) {
  __shared__ float lps[64 * 32];
  const int s = blockIdx.x;
  const int h = s >> 3, w = s & 7;
  const int b0 = blockIdx.y * 64;
  const int t = threadIdx.x;
  const int c = t & 127;
  const int half = t >> 7;
  float4 zr[8];
  const float4* zp = (const float4*)(z + (size_t)(c * 64 + s) * 32);
  #pragma unroll
  for (int i = 0; i < 8; ++i) zr[i] = zp[i];
  #pragma unroll
  for (int i = 0; i < 8; ++i) lps[t + 256 * i] = lp[b0 * 32 + t + 256 * i];
  __syncthreads();
  for (int bs = 0; bs < 32; ++bs) {
    int bl = half * 32 + bs;
    const float4* lr = (const float4*)(lps + bl * 32);
    float acc = 0.f;
    #pragma unroll
    for (int i = 0; i < 8; ++i) {
      float4 l4 = lr[i];
      acc += zr[i].x * l4.x + zr[i].y * l4.y + zr[i].z * l4.z + zr[i].w * l4.w;
    }
    int b = b0 + bl;
    x1[((size_t)(b * 10 + h + 1) * 10 + (w + 1)) * 128 + c] = __float2bfloat16(acc);
  }
}

// ---------------- single-parity-per-wave 32x32 transposed conv (conv1, conv2) ----------------
// 512-thread block = 8 waves = 4 parities x 2 N-halves, sharing one LDS A-tile (fetched once).
// Each wave: M=128 (MI=4 m-tiles), N=32, one parity. B fragment loaded once per (tap,kstep)
// from global (L1/L2-resident wt) and reused across MI=4 MFMAs -> 4x less B traffic than r8.
// acc = MI*16 = 64 regs; only one __syncthreads (after A staging).
template<int IC, int OCp, int IH, int IW, int ROWS, int IMGS>
__global__ __launch_bounds__(512, 4)
void convt32s(const bf16* __restrict__ xin, const bf16* __restrict__ wt,
              const float* __restrict__ bias, bf16* __restrict__ xout) {
  constexpr int KG = IC / 8;
  constexpr int NS = IC / 16;            // k16 steps per tap
  constexpr int IH2 = IH + 2, IW2 = IW + 2;
  constexpr int OH2 = 2 * IH + 2, OW2 = 2 * IW + 2;
  constexpr int TPIX = (ROWS + 2) * IW2; // pixels per image tile (incl halo)
  constexpr int NPIXT = IMGS * TPIX;
  constexpr int BPI = IH / ROWS;
  constexpr int MI = IMGS * ROWS * IW / 32;  // 4
  constexpr int LIW = (IW == 8 ? 3 : 4);
  constexpr int ICV = IC / 8;
  __shared__ bf16 Alds[KG * NPIXT * 8];

  const int tid = threadIdx.x;
  const int wave = tid >> 6, lane = tid & 63;
  const int l32 = lane & 31, hl = lane >> 5;
  const int p = wave & 3, nh = wave >> 2;
  const int py = p >> 1, px = p & 1;
  const int bm = blockIdx.x;
  const int img0 = (bm / BPI) * IMGS, tb = bm % BPI;
  const int n0 = blockIdx.y * 64 + nh * 32;

  // ---- stage A tile(s): global [pix][ic] -> LDS [kg][imgtile*TPIX+pix][8] ----
  #pragma unroll
  for (int i = 0; i < IMGS; ++i) {
    const bf16* src = xin + ((size_t)(img0 + i) * IH2 + tb * ROWS) * IW2 * IC;
    for (int g = tid; g < TPIX * ICV; g += 512) {
      const int pix = g / ICV;
      const int gr = g % ICV;
      const float4 v = *(const float4*)(src + (size_t)g * 8);
      *(float4*)(&Alds[(gr * NPIXT + i * TPIX + pix) * 8]) = v;
    }
  }

  // per-mi A base pointers (lane l32 = m-row within 32)
  const bf16* ap[MI];
  #pragma unroll
  for (int mi = 0; mi < MI; ++mi) {
    const int m = mi * 32 + l32;
    const int il = m / (ROWS * IW);
    const int mm = m % (ROWS * IW);
    const int pix = il * TPIX + ((mm >> LIW) + 1) * IW2 + (mm & (IW - 1)) + 1;
    ap[mi] = Alds + ((size_t)(hl * NPIXT + pix)) * 8;
  }
  // per-lane B pointer (oc = n0 + l32, chunk base p*4, kg parity hl)
  const bf16* wp = wt + ((size_t)((p * 4 * KG) + hl) * OCp + n0 + l32) * 8;

  f32x16 acc[MI];
  #pragma unroll
  for (int mi = 0; mi < MI; ++mi)
    #pragma unroll
    for (int r = 0; r < 16; ++r) acc[mi][r] = 0.f;

  auto ldB = [&](int kk) -> bf16x8 {
    const int tap = kk >> 3, s = kk & 7;   // NS==8
    return *(const bf16x8*)(wp + ((size_t)(tap * KG + s * 2) * OCp) * 8);
  };

  bf16x8 bc = ldB(0);
  __syncthreads();   // A tile ready; only barrier

  #pragma unroll
  for (int kk = 0; kk < 4 * NS; ++kk) {
    const bf16x8 bn = (kk + 1 < 4 * NS) ? ldB(kk + 1) : bc;
    const int tap = kk >> 3, s = kk & 7;
    const int dy = tap >> 1, dx = tap & 1;
    const int sh = (dy ? (py ? 1 : -1) * IW2 : 0) + (dx ? (px ? 1 : -1) : 0);
    #pragma unroll
    for (int mi = 0; mi < MI; ++mi) {
      const bf16x8 a = *(const bf16x8*)(ap[mi] + (s * 2 * NPIXT + sh) * 8);
      acc[mi] = __builtin_amdgcn_mfma_f32_32x32x16_bf16(a, bc, acc[mi], 0, 0, 0);
    }
    bc = bn;
  }

  // ---- epilogue: C/D col = l32 (oc), row = (r&3) + 8*(r>>2) + 4*hl ----
  const int oc = n0 + l32;
  const float bv = bias[oc];
  #pragma unroll
  for (int mi = 0; mi < MI; ++mi) {
    #pragma unroll
    for (int r = 0; r < 16; ++r) {
      const int ml = mi * 32 + (r & 3) + 8 * (r >> 2) + 4 * hl;
      const int il = ml / (ROWS * IW);
      const int mm = ml % (ROWS * IW);
      const int y = tb * ROWS + (mm >> LIW), x = mm & (IW - 1);
      float v = fmaxf(acc[mi][r] + bv, 0.f);
      xout[(((size_t)(img0 + il) * OH2 + 2 * y + py + 1) * OW2 + 2 * x + px + 1) * OCp + oc] =
          __float2bfloat16(v);
    }
  }
}

// ---------------- 16x16x32 conv3 (N=16, fp32 NCHW out) — unchanged from round 8 ----------------
__global__ __launch_bounds__(256, 3)
void convt16_final(const bf16* __restrict__ xin, const bf16* __restrict__ wt,
                   const float* __restrict__ bias, float* __restrict__ fout) {
  constexpr int IC = 64, OCp = 16, OCr = 3, IH = 32, IW = 32, ROWS = 8;
  constexpr int KG = IC / 8;
  constexpr int NC = IC / 32;
  constexpr int IH2 = IH + 2, IW2 = IW + 2;
  constexpr int NPIX = (ROWS + 2) * IW2;
  constexpr int BPI = IH / ROWS;
  constexpr int MI = 4;
  constexpr int ICV = IC / 8;
  __shared__ bf16 Alds[KG * NPIX * 8];

  const int tid = threadIdx.x;
  const int wave = tid >> 6, lane = tid & 63;
  const int q = lane >> 4, li = lane & 15;
  const int img = blockIdx.x / BPI;
  const int tb = blockIdx.x % BPI;

  const bf16* src = xin + ((size_t)img * IH2 + tb * ROWS) * IW2 * IC;
  for (int g = tid; g < NPIX * ICV; g += 256) {
    const int pix = g / ICV;
    const int gr = g % ICV;
    const float4 v = *(const float4*)(src + (size_t)g * 8);
    *(float4*)(&Alds[(gr * NPIX + pix) * 8]) = v;
  }

  int cpix[MI];
  #pragma unroll
  for (int mi = 0; mi < MI; ++mi) {
    const int m = wave * 64 + mi * 16 + li;
    cpix[mi] = ((m >> 5) + 1) * IW2 + (m & 31) + 1;
  }
  const bf16* wtp = wt + (size_t)li * 8;

  f32x4 acc[4][MI];
  #pragma unroll
  for (int p = 0; p < 4; ++p)
    #pragma unroll
    for (int mi = 0; mi < MI; ++mi)
      acc[p][mi] = (f32x4){0.f, 0.f, 0.f, 0.f};

  constexpr int TAPA[9] = {0, 1, 1, 2, 2, 3, 3, 3, 3};
  constexpr int DYA[9]  = {0, 0, 0,-1, 1,-1,-1, 1, 1};
  constexpr int DXA[9]  = {0,-1, 1, 0, 0,-1, 1,-1, 1};
  constexpr int MSK[9]  = {0xF,0x5,0xA,0x3,0xC,0x1,0x2,0x4,0x8};
  __syncthreads();

  #pragma unroll
  for (int e = 0; e < 9; ++e) {
    const int tap = TAPA[e];
    const int sh = (DYA[e] * IW2 + DXA[e]);
    #pragma unroll
    for (int c = 0; c < NC; ++c) {
      bf16x8 bfr[4];
      #pragma unroll
      for (int p = 0; p < 4; ++p)
        if (MSK[e] & (1 << p))
          bfr[p] = *(const bf16x8*)(wtp + ((size_t)((p * 4 + tap) * KG + c * 4 + q) * OCp) * 8);
      #pragma unroll
      for (int mi = 0; mi < MI; ++mi) {
        const bf16x8 a = *(const bf16x8*)(Alds + (((c * 4 + q) * NPIX) + cpix[mi] + sh) * 8);
        #pragma unroll
        for (int p = 0; p < 4; ++p)
          if (MSK[e] & (1 << p))
            acc[p][mi] = __builtin_amdgcn_mfma_f32_16x16x32_bf16(a, bfr[p], acc[p][mi], 0, 0, 0);
      }
    }
  }

  const int oc = li;
  if (oc < OCr) {
    const float bv = bias[oc];
    #pragma unroll
    for (int py = 0; py < 2; ++py)
      #pragma unroll
      for (int mi = 0; mi < MI; ++mi)
        #pragma unroll
        for (int r = 0; r < 4; ++r) {
          const int pix = (wave * MI + mi) * 16 + q * 4 + r;
          const int y = tb * ROWS + (pix >> 5), x = pix & 31;
          float2 v2;
          v2.x = acc[py * 2 + 0][mi][r] + bv;
          v2.y = acc[py * 2 + 1][mi][r] + bv;
          *(float2*)(&fout[(((size_t)img * 3 + oc) * 64 + 2 * y + py) * 64 + 2 * x]) = v2;
        }
  }
}

// ---------------- launch ----------------
extern "C" void kernel_launch(void* const* d_in, const int* in_sizes, int n_in,
                              void* d_out, int out_size, void* d_ws, size_t ws_size,
                              hipStream_t stream) {
  const float* x  = (const float*)d_in[0];
  const float* gw = (const float*)d_in[1];
  const float* gb = (const float*)d_in[2];
  const float* z  = (const float*)d_in[3];
  const float* w1 = (const float*)d_in[4];
  const float* b1 = (const float*)d_in[5];
  const float* w2 = (const float*)d_in[6];
  const float* b2 = (const float*)d_in[7];
  const float* w3 = (const float*)d_in[8];
  const float* b3 = (const float*)d_in[9];
  float* out = (float*)d_out;

  char* w = (char*)d_ws;
  float* lp  = (float*)(w);
  bf16* x1  = (bf16*)(w + 65536);
  bf16* x2  = (bf16*)(w + 13172736);
  bf16* x3  = (bf16*)(w + 55640064);
  bf16* wt1 = (bf16*)(w + 131399680);
  bf16* wt2 = (bf16*)(w + 131923968);
  bf16* wt3 = (bf16*)(w + 132186112);

  prep_kernel<<<NB_Z1 + NB_Z2 + NB_Z3 + NB_W1 + NB_W2 + NB_W3 + NB_G, 256, 0, stream>>>(
      x1, x2, x3, w1, wt1, w2, wt2, w3, wt3, x, gw, gb, lp);

  mixture_kernel<<<dim3(64, 8), 256, 0, stream>>>(z, lp, x1);

  // conv1: 128->128, 8x8 -> 16x16. IMGS=2 -> M=128/block, N=64/block (grid-y 2). 512 blocks.
  convt32s<128, 128, 8, 8, 8, 2><<<dim3(256, 2), 512, 0, stream>>>(x1, wt1, b1, x2);
  // conv2: 128->64, 16x16 -> 32x32. ROWS=8 -> M=128/block, N=64 full. 1024 blocks.
  convt32s<128, 64, 16, 16, 8, 1><<<dim3(1024, 1), 512, 0, stream>>>(x2, wt2, b2, x3);
  // conv3: 64->3(pad16), 32x32 -> 64x64, fp32 NCHW. unchanged r8. 2048 blocks.
  convt16_final<<<dim3(2048, 1), 256, 0, stream>>>(x3, wt3, b3, out);
}